// Round 12
// baseline (220.807 us; speedup 1.0000x reference)
//
#include <hip/hip_runtime.h>
#include <hip/hip_bf16.h>
#include <stdint.h>

#define EPSF 1e-5f

typedef __attribute__((ext_vector_type(4))) int i32x4;
typedef __attribute__((ext_vector_type(8))) int i32x8;
typedef __attribute__((ext_vector_type(16))) float f32x16;
typedef __attribute__((ext_vector_type(16))) char c8x16;

__device__ __forceinline__ void gld_lds16(const void* g, void* l) {
  __builtin_amdgcn_global_load_lds((const __attribute__((address_space(1))) void*)g,
                                   (__attribute__((address_space(3))) void*)l, 16, 0, 0);
}

__device__ __forceinline__ i32x8 dup8(i32x4 t) {
  i32x8 a;
  a[0] = t[0]; a[1] = t[1]; a[2] = t[2]; a[3] = t[3];
  a[4] = t[0]; a[5] = t[1]; a[6] = t[2]; a[7] = t[3];
  return a;
}

// (a,b,c, cbsz=4(fp4), blgp=4(fp4), opselA=0, scaleA, opselB=0, scaleB); scale byte 0x7F = 1.0
#define MFMA_FP4(a, b, c) \
  __builtin_amdgcn_mfma_scale_f32_32x32x64_f8f6f4((a), (b), (c), 4, 4, 0, 0x7F7F7F7F, 0, 0x7F7F7F7F)

// ---------------- probe (R9-verified, standalone 64 threads): slot pairing T + lambda ----------------
__global__ void k_probe(unsigned char* __restrict__ T, float* __restrict__ lam_inv) {
  const int l = threadIdx.x;  // 64
  const int half = l >> 5, c31 = l & 31;
  const int byteidx = c31 >> 1;
  const int dw = byteidx >> 2;
  const int sh = (byteidx & 3) * 8 + (c31 & 1) * 4;
  const int hot = 0x2 << sh;
#pragma unroll
  for (int pa = 0; pa < 2; ++pa) {
#pragma unroll
    for (int pb = 0; pb < 2; ++pb) {
      i32x8 a = (i32x8)0, b = (i32x8)0;
      if (half == pa) { a[dw] = hot; a[dw + 4] = hot; }
      if (half == pb) { b[dw] = hot; b[dw + 4] = hot; }
      f32x16 c = (f32x16)0.0f;
      c = MFMA_FP4(a, b, c);
#pragma unroll
      for (int r = 0; r < 16; ++r) {
        if (c[r] != 0.0f) {
          const int row = (r & 3) + 8 * (r >> 2) + 4 * half;
          T[pb * 32 + c31] = (unsigned char)(pa * 16 + (row >> 1) + 32 * (row & 1));
        }
      }
    }
  }
  i32x8 a1;
#pragma unroll
  for (int j = 0; j < 8; ++j) a1[j] = 0x22222222;
  f32x16 c = (f32x16)0.0f;
  c = MFMA_FP4(a1, a1, c);
  if (l == 0) *lam_inv = __fdiv_rn(64.0f, c[0]);
}

// ---------------- activation pack: f32 [rows x Ksrc] -> fp4 pi-order [rows x 512B] ----------------
__global__ void k_pack(const float* __restrict__ src, unsigned char* __restrict__ dst,
                       int Ksrc, float thr) {
  int t = blockIdx.x * 256 + threadIdx.x;
  int row = t >> 5, ch = t & 31;
  int g = ch >> 1, jb = (ch & 1) << 4;
  int c0 = g * 64 + jb, c1 = c0 + 32;
  c8x16 o = (c8x16)0;
  const float* p = src + (size_t)row * Ksrc;
  const bool v0 = (c0 + 16) <= Ksrc;
  const bool v1 = (c1 + 16) <= Ksrc;
  float lo[16], hi[16];
  if (v0) {
    *(float4*)(lo + 0) = *(const float4*)(p + c0 + 0);
    *(float4*)(lo + 4) = *(const float4*)(p + c0 + 4);
    *(float4*)(lo + 8) = *(const float4*)(p + c0 + 8);
    *(float4*)(lo + 12) = *(const float4*)(p + c0 + 12);
  }
  if (v1) {
    *(float4*)(hi + 0) = *(const float4*)(p + c1 + 0);
    *(float4*)(hi + 4) = *(const float4*)(p + c1 + 4);
    *(float4*)(hi + 8) = *(const float4*)(p + c1 + 8);
    *(float4*)(hi + 12) = *(const float4*)(p + c1 + 12);
  }
#pragma unroll
  for (int e = 0; e < 16; ++e) {
    unsigned nl = v0 ? ((lo[e] >= thr) ? 2u : 10u) : 0u;
    unsigned nh = v1 ? ((hi[e] >= thr) ? 2u : 10u) : 0u;
    o[e] = (char)(nl | (nh << 4));
  }
  *(c8x16*)(dst + (size_t)t * 16) = o;
}

// ---------------- weight pack THROUGH T (R9-verified): y=0..2 hidden weights ----------------
__global__ void k_packW(const float* __restrict__ W0, const float* __restrict__ Wh,
                        const unsigned char* __restrict__ T, unsigned char* __restrict__ dstbase) {
  const int y = blockIdx.y;
  const float* src = (y == 0) ? W0 : (Wh + (size_t)(y - 1) * 1048576);
  const int Ksrc = (y == 0) ? 784 : 1024;
  unsigned char* dst = dstbase + (size_t)y * 524288;
  int t = blockIdx.x * 256 + threadIdx.x;
  int w = t >> 5, g = (t >> 1) & 15, h = t & 1;
  const float* p = src + (size_t)w * Ksrc + g * 64;
  const int base = g * 64;
  c8x16 o;
#pragma unroll
  for (int b = 0; b < 16; ++b) {
    unsigned byte = 0;
#pragma unroll
    for (int n = 0; n < 2; ++n) {
      int k = T[h * 32 + 2 * b + n];
      int col = base + k;
      unsigned nib = 0;
      if (col < Ksrc) nib = (p[k] >= 0.0f) ? 2u : 10u;
      byte |= nib << (4 * n);
    }
    o[b] = (char)byte;
  }
  *(c8x16*)(dst + (size_t)w * 512 + g * 32 + h * 16) = o;
}

// ---------------- small prep (R9-verified): inv_std + binarized WL [16][1024] i8 ----------------
__global__ void k_prep(const float* __restrict__ bn_gamma, const float* __restrict__ bn_var,
                       const float* __restrict__ bnL_gamma, const float* __restrict__ bnL_var,
                       const float* __restrict__ WL,
                       float* __restrict__ invstd3, float* __restrict__ invstdL,
                       char* __restrict__ WLb) {
  int j = threadIdx.x;
#pragma unroll
  for (int i = 0; i < 3; ++i) {
    int idx = i * 1024 + j;
    invstd3[idx] = __fdiv_rn(bn_gamma[idx], __fsqrt_rn(__fadd_rn(bn_var[idx], EPSF)));
  }
  if (j < 10) invstdL[j] = __fdiv_rn(bnL_gamma[j], __fsqrt_rn(__fadd_rn(bnL_var[j], EPSF)));
#pragma unroll
  for (int r = 0; r < 16; ++r) {
    char v = 0;
    if (r < 10) v = (WL[r * 1024 + j] >= 0.0f) ? (char)1 : (char)-1;
    WLb[r * 1024 + j] = v;
  }
}

// ---------------- main fused GEMM (fp4): ONE change vs R9 -- BK window 256B (2 intervals) ----------------
// 128x128 tile, 4 waves 2x2, LDS 64KB: A sub-windows at 0/16384, B at 32768/49152, each
// [128 rows][128B] with the verified linear-dest + in-row XOR chunk swizzle. 16 gld_lds +
// 8 MFMA-steps (32 MFMA) per interval per wave, two __syncthreads per interval.
// li from k_probe's lam_inv (R9-verified path). Epilogue unchanged from R9.
template <int OUT_I8>
__global__ __launch_bounds__(256, 2)
void gemm_bin(const unsigned char* __restrict__ A, const unsigned char* __restrict__ Bt,
              unsigned char* __restrict__ Cb,
              const float* __restrict__ mean, const float* __restrict__ beta,
              const float* __restrict__ invstd, const float* __restrict__ lam_inv) {
  __shared__ char lds[65536];
  const int tid = threadIdx.x;
  const int lane = tid & 63;
  const int wave = tid >> 6;
  const int d = blockIdx.x;  // 0..4095
  const int xcd = d & 7;
  const int idx = d >> 3;
  const int bm = xcd * 64 + (idx >> 3);
  const int bn = idx & 7;
  const int wm = wave >> 1, wn = wave & 1;
  const int h = lane >> 5, r31 = lane & 31;

  const int srow = tid >> 3;  // 0..31
  const int schunk = ((tid & 7) ^ (srow & 7)) << 4;
  const unsigned char* gA = A + (size_t)(bm * 128 + srow) * 512 + schunk;
  const unsigned char* gB = Bt + (size_t)(bn * 128 + srow) * 512 + schunk;
  const int lwoff = (tid & ~63) * 16;

  const float li = *lam_inv;

  f32x16 acc00 = (f32x16)0.0f, acc01 = (f32x16)0.0f;
  f32x16 acc10 = (f32x16)0.0f, acc11 = (f32x16)0.0f;

  const int arow = (wm * 64 + r31) * 128;  // + mt*4096 (32 rows)
  const int brow = (wn * 64 + r31) * 128;  // + nt*4096

#pragma unroll
  for (int t = 0; t < 2; ++t) {
    const int ko = t * 256;
#pragma unroll
    for (int w = 0; w < 2; ++w) {
#pragma unroll
      for (int i = 0; i < 4; ++i) {
        gld_lds16(gA + ko + w * 128 + i * 16384, lds + w * 16384 + lwoff + i * 4096);
        gld_lds16(gB + ko + w * 128 + i * 16384, lds + 32768 + w * 16384 + lwoff + i * 4096);
      }
    }
    __syncthreads();
#pragma unroll
    for (int s = 0; s < 8; ++s) {
      const int subw = (s >> 2) * 16384;
      const int slot = ((((s & 3) << 1) + h) ^ (r31 & 7)) << 4;
      const int ab = subw + arow + slot;
      const int bb = 32768 + subw + brow + slot;
      i32x8 a0 = dup8(*(const i32x4*)(lds + ab));
      i32x8 a1 = dup8(*(const i32x4*)(lds + ab + 4096));
      i32x8 b0 = dup8(*(const i32x4*)(lds + bb));
      i32x8 b1 = dup8(*(const i32x4*)(lds + bb + 4096));
      acc00 = MFMA_FP4(a0, b0, acc00);
      acc01 = MFMA_FP4(a0, b1, acc01);
      acc10 = MFMA_FP4(a1, b0, acc10);
      acc11 = MFMA_FP4(a1, b1, acc11);
    }
    __syncthreads();
  }

  // epilogue (R9-identical): acc*(1/lam) exact; BN numpy-f32 rounding; binarize
  const int rbase = bm * 128 + wm * 64 + 4 * h;
  const int c0 = bn * 128 + wn * 64 + r31;
  const float mu0 = mean[c0], is0 = invstd[c0], be0 = beta[c0];
  const float mu1 = mean[c0 + 32], is1 = invstd[c0 + 32], be1 = beta[c0 + 32];
  const int cb = bn * 64 + wn * 32 + r31;
#pragma unroll
  for (int mt = 0; mt < 2; ++mt) {
    const f32x16 a0 = (mt == 0) ? acc00 : acc10;
    const f32x16 a1 = (mt == 0) ? acc01 : acc11;
#pragma unroll
    for (int r = 0; r < 16; ++r) {
      const int row = rbase + mt * 32 + (r & 3) + 8 * (r >> 2);
      float y0 = __fadd_rn(__fmul_rn(__fsub_rn(__fmul_rn(a0[r], li), mu0), is0), be0);
      float y1 = __fadd_rn(__fmul_rn(__fsub_rn(__fmul_rn(a1[r], li), mu1), is1), be1);
      if (OUT_I8) {
        Cb[(size_t)row * 1024 + c0] = (y0 >= 0.0f) ? 1 : 0xFF;
        Cb[(size_t)row * 1024 + c0 + 32] = (y1 >= 0.0f) ? 1 : 0xFF;
      } else {
        unsigned nl = (y0 >= 0.0f) ? 2u : 10u;
        unsigned nh = (y1 >= 0.0f) ? 2u : 10u;
        Cb[(size_t)row * 512 + cb] = (unsigned char)(nl | (nh << 4));
      }
    }
  }
}

// ---------------- final layer: out[65536][10] = BN(A @ WLb^T), fp32 out, i8 inputs (R2-verified) ----
__global__ __launch_bounds__(256, 2)
void gemm_fin(const char* __restrict__ A, const char* __restrict__ BtL,
              float* __restrict__ out,
              const float* __restrict__ meanL, const float* __restrict__ betaL,
              const float* __restrict__ invstdL) {
  constexpr int K = 1024;
  __shared__ char sA[128 * 64];
  __shared__ char sB[16 * 64];
  const int tid = threadIdx.x;
  const int lane = tid & 63;
  const int wave = tid >> 6;
  const int bm = blockIdx.x;

  const int sr = tid >> 2;
  const int csrc = ((tid & 3) ^ (sr & 3)) << 4;
  const char* gA = A + (size_t)(bm * 128 + sr) * K + csrc;
  const char* gB = BtL + (size_t)sr * K + csrc;
  char* lA = sA + (tid & ~63) * 16;
  char* lB = sB;

  const int slot = ((lane >> 4) ^ (lane & 3)) << 4;
  const char* rA = sA + (wave * 32 + (lane & 15)) * 64 + slot;
  const char* rB = sB + (lane & 15) * 64 + slot;

  i32x4 acc0 = (i32x4)0, acc1 = (i32x4)0;

  for (int k0 = 0; k0 < K; k0 += 64) {
    gld_lds16(gA, lA);
    gld_lds16(gA + (size_t)64 * K, lA + 4096);
    if (tid < 64) gld_lds16(gB, lB);
    gA += 64;
    gB += 64;
    __syncthreads();
    i32x4 af0 = *(const i32x4*)(rA);
    i32x4 af1 = *(const i32x4*)(rA + 16 * 64);
    i32x4 b0 = *(const i32x4*)(rB);
    acc0 = __builtin_amdgcn_mfma_i32_16x16x64_i8(af0, b0, acc0, 0, 0, 0);
    acc1 = __builtin_amdgcn_mfma_i32_16x16x64_i8(af1, b0, acc1, 0, 0, 0);
    __syncthreads();
  }

  const int col = lane & 15;
  if (col < 10) {
    const float mu = meanL[col], is = invstdL[col], be = betaL[col];
    const int r0 = bm * 128 + wave * 32 + ((lane >> 4) << 2);
#pragma unroll
    for (int m = 0; m < 2; ++m) {
      const i32x4 a = (m == 0) ? acc0 : acc1;
#pragma unroll
      for (int j = 0; j < 4; ++j) {
        const int row = r0 + m * 16 + j;
        out[(size_t)row * 10 + col] = __fadd_rn(__fmul_rn(__fsub_rn((float)a[j], mu), is), be);
      }
    }
  }
}

extern "C" void kernel_launch(void* const* d_in, const int* in_sizes, int n_in,
                              void* d_out, int out_size, void* d_ws, size_t ws_size,
                              hipStream_t stream) {
  const float* x = (const float*)d_in[0];
  const float* W0 = (const float*)d_in[1];
  const float* Wh = (const float*)d_in[2];
  const float* WL = (const float*)d_in[3];
  const float* bn_gamma = (const float*)d_in[4];
  const float* bn_beta = (const float*)d_in[5];
  const float* bn_mean = (const float*)d_in[6];
  const float* bn_var = (const float*)d_in[7];
  const float* bnL_gamma = (const float*)d_in[8];
  const float* bnL_beta = (const float*)d_in[9];
  const float* bnL_mean = (const float*)d_in[10];
  const float* bnL_var = (const float*)d_in[11];
  float* out = (float*)d_out;

  // workspace (R9-identical layout, ~130 MB)
  char* ws = (char*)d_ws;
  unsigned char* X0f4 = (unsigned char*)ws;                    // 32 MiB
  unsigned char* X1f4 = (unsigned char*)(ws + 33554432);       // 32 MiB
  unsigned char* Xi8 = (unsigned char*)(ws + 67108864);        // 64 MiB
  char* wbase = ws + 134217728;
  unsigned char* Wf4 = (unsigned char*)wbase;                  // 3 x 512 KiB
  char* WLb = wbase + 3 * 524288;                              // 16 KiB
  float* invstd3 = (float*)(wbase + 3 * 524288 + 16384);       // 12 KiB
  float* invstdL = invstd3 + 3 * 1024;
  float* lam_inv = invstdL + 16;
  unsigned char* T = (unsigned char*)(lam_inv + 16);           // 64 B

  hipLaunchKernelGGL(k_prep, dim3(1), dim3(1024), 0, stream,
                     bn_gamma, bn_var, bnL_gamma, bnL_var, WL, invstd3, invstdL, WLb);
  hipLaunchKernelGGL(k_probe, dim3(1), dim3(64), 0, stream, T, lam_inv);
  hipLaunchKernelGGL(k_packW, dim3(128, 3), dim3(256), 0, stream, W0, Wh, T, Wf4);
  hipLaunchKernelGGL(k_pack, dim3(8192), dim3(256), 0, stream, x, X0f4, 784, 0.5f);

  hipLaunchKernelGGL((gemm_bin<0>), dim3(4096), dim3(256), 0, stream, X0f4, Wf4, X1f4,
                     bn_mean, bn_beta, invstd3, lam_inv);
  hipLaunchKernelGGL((gemm_bin<0>), dim3(4096), dim3(256), 0, stream, X1f4, Wf4 + 524288, X0f4,
                     bn_mean + 1024, bn_beta + 1024, invstd3 + 1024, lam_inv);
  hipLaunchKernelGGL((gemm_bin<1>), dim3(4096), dim3(256), 0, stream, X0f4, Wf4 + 2 * 524288, Xi8,
                     bn_mean + 2048, bn_beta + 2048, invstd3 + 2048, lam_inv);
  hipLaunchKernelGGL(gemm_fin, dim3(512), dim3(256), 0, stream, (const char*)Xi8, (const char*)WLb,
                     out, bnL_mean, bnL_beta, invstdL);
}

// Round 15
// 197.937 us; speedup vs baseline: 1.1155x; 1.1155x over previous
//
#include <hip/hip_runtime.h>
#include <hip/hip_bf16.h>
#include <stdint.h>

#define EPSF 1e-5f

typedef __attribute__((ext_vector_type(4))) int i32x4;
typedef __attribute__((ext_vector_type(8))) int i32x8;
typedef __attribute__((ext_vector_type(16))) float f32x16;
typedef __attribute__((ext_vector_type(16))) char c8x16;

__device__ __forceinline__ void gld_lds16(const void* g, void* l) {
  __builtin_amdgcn_global_load_lds((const __attribute__((address_space(1))) void*)g,
                                   (__attribute__((address_space(3))) void*)l, 16, 0, 0);
}

__device__ __forceinline__ i32x8 dup8(i32x4 t) {
  i32x8 a;
  a[0] = t[0]; a[1] = t[1]; a[2] = t[2]; a[3] = t[3];
  a[4] = t[0]; a[5] = t[1]; a[6] = t[2]; a[7] = t[3];
  return a;
}

// R3-verified-compiling form: (a,b,c, cbsz=4(fp4), blgp=4(fp4), opselA=0, scaleA, opselB=0, scaleB)
// scale dwords all-0x7F: selected byte = 0x7F = 1.0 (e8m0).
#define MFMA_FP4(a, b, c) \
  __builtin_amdgcn_mfma_scale_f32_32x32x64_f8f6f4((a), (b), (c), 4, 4, 0, 0x7F7F7F7F, 0, 0x7F7F7F7F)

// ---------------- probe: discover A/B slot pairing + lambda, fully on-device ----------------
// Slot (h,b,n): lane half h, register byte b (0..15), nibble n. A-side logical (pi) order:
// myA(h,b,n) = h*16 + b + 32*n (within a 64-k window). Probe finds for every B slot the paired
// A slot; T[h*32 + 2b + n] = myA(paired A slot). Then lam via all-ones MFMA (lam_inv exact pow2).
__global__ void k_probe(unsigned char* __restrict__ T, float* __restrict__ lam_inv) {
  const int l = threadIdx.x;  // 64
  const int half = l >> 5, c31 = l & 31;
  const int byteidx = c31 >> 1;
  const int dw = byteidx >> 2;
  const int sh = (byteidx & 3) * 8 + (c31 & 1) * 4;
  const int hot = 0x2 << sh;  // +1.0 e2m1 nibble
#pragma unroll
  for (int pa = 0; pa < 2; ++pa) {
#pragma unroll
    for (int pb = 0; pb < 2; ++pb) {
      i32x8 a = (i32x8)0, b = (i32x8)0;
      if (half == pa) { a[dw] = hot; a[dw + 4] = hot; }
      if (half == pb) { b[dw] = hot; b[dw + 4] = hot; }
      f32x16 c = (f32x16)0.0f;
      c = MFMA_FP4(a, b, c);
#pragma unroll
      for (int r = 0; r < 16; ++r) {
        if (c[r] != 0.0f) {
          const int row = (r & 3) + 8 * (r >> 2) + 4 * half;  // verified 32x32 C/D map
          T[pb * 32 + c31] = (unsigned char)(pa * 16 + (row >> 1) + 32 * (row & 1));
        }
      }
    }
  }
  // lambda: all-ones -> acc = 64*lam (covers any uniform multiplicity/scale)
  i32x8 a1;
#pragma unroll
  for (int j = 0; j < 8; ++j) a1[j] = 0x22222222;
  f32x16 c = (f32x16)0.0f;
  c = MFMA_FP4(a1, a1, c);
  if (l == 0) *lam_inv = __fdiv_rn(64.0f, c[0]);
}

// ---------------- activation pack: f32 [rows x Ksrc] -> fp4 pi-order [rows x 512B] ----------------
// byte B of row: g=B>>5, j=B&31 -> lo nib = sign(src[g*64+j]), hi = sign(src[g*64+j+32]).
// +1 -> 0x2, -1 -> 0xA; out-of-range -> 0x0. thr = 0.5 maps sign(2x-1) exactly.
__global__ void k_pack(const float* __restrict__ src, unsigned char* __restrict__ dst,
                       int Ksrc, float thr) {
  int t = blockIdx.x * 256 + threadIdx.x;  // rows*32 threads
  int row = t >> 5, ch = t & 31;
  int g = ch >> 1, jb = (ch & 1) << 4;
  int c0 = g * 64 + jb, c1 = c0 + 32;
  c8x16 o = (c8x16)0;
  const float* p = src + (size_t)row * Ksrc;
  const bool v0 = (c0 + 16) <= Ksrc;
  const bool v1 = (c1 + 16) <= Ksrc;
  float lo[16], hi[16];
  if (v0) {
    *(float4*)(lo + 0) = *(const float4*)(p + c0 + 0);
    *(float4*)(lo + 4) = *(const float4*)(p + c0 + 4);
    *(float4*)(lo + 8) = *(const float4*)(p + c0 + 8);
    *(float4*)(lo + 12) = *(const float4*)(p + c0 + 12);
  }
  if (v1) {
    *(float4*)(hi + 0) = *(const float4*)(p + c1 + 0);
    *(float4*)(hi + 4) = *(const float4*)(p + c1 + 4);
    *(float4*)(hi + 8) = *(const float4*)(p + c1 + 8);
    *(float4*)(hi + 12) = *(const float4*)(p + c1 + 12);
  }
#pragma unroll
  for (int e = 0; e < 16; ++e) {
    unsigned nl = v0 ? ((lo[e] >= thr) ? 2u : 10u) : 0u;
    unsigned nh = v1 ? ((hi[e] >= thr) ? 2u : 10u) : 0u;
    o[e] = (char)(nl | (nh << 4));
  }
  *(c8x16*)(dst + (size_t)t * 16) = o;
}

// ---------------- weight pack THROUGH discovered table T ----------------
// B slot (h,b,n) of window g gets W[w, g*64 + T[h*32+2b+n]]; packed byte = w*512 + g*32 + h*16 + b.
__global__ void k_packW(const float* __restrict__ W0, const float* __restrict__ Wh,
                        const unsigned char* __restrict__ T, unsigned char* __restrict__ dstbase) {
  const int y = blockIdx.y;
  const float* src = (y == 0) ? W0 : (Wh + (size_t)(y - 1) * 1048576);
  const int Ksrc = (y == 0) ? 784 : 1024;
  unsigned char* dst = dstbase + (size_t)y * 524288;
  int t = blockIdx.x * 256 + threadIdx.x;  // 32768: w = t>>5, g = (t>>1)&15, h = t&1
  int w = t >> 5, g = (t >> 1) & 15, h = t & 1;
  const float* p = src + (size_t)w * Ksrc + g * 64;
  const int base = g * 64;
  c8x16 o;
#pragma unroll
  for (int b = 0; b < 16; ++b) {
    unsigned byte = 0;
#pragma unroll
    for (int n = 0; n < 2; ++n) {
      int k = T[h * 32 + 2 * b + n];
      int col = base + k;
      unsigned nib = 0;
      if (col < Ksrc) nib = (p[k] >= 0.0f) ? 2u : 10u;
      byte |= nib << (4 * n);
    }
    o[b] = (char)byte;
  }
  *(c8x16*)(dst + (size_t)w * 512 + g * 32 + h * 16) = o;
}

// ---------------- small prep: inv_std (exact numpy f32 rounding) + binarized WL [16][1024] i8 ----------------
__global__ void k_prep(const float* __restrict__ bn_gamma, const float* __restrict__ bn_var,
                       const float* __restrict__ bnL_gamma, const float* __restrict__ bnL_var,
                       const float* __restrict__ WL,
                       float* __restrict__ invstd3, float* __restrict__ invstdL,
                       char* __restrict__ WLb) {
  int j = threadIdx.x;
#pragma unroll
  for (int i = 0; i < 3; ++i) {
    int idx = i * 1024 + j;
    invstd3[idx] = __fdiv_rn(bn_gamma[idx], __fsqrt_rn(__fadd_rn(bn_var[idx], EPSF)));
  }
  if (j < 10) invstdL[j] = __fdiv_rn(bnL_gamma[j], __fsqrt_rn(__fadd_rn(bnL_var[j], EPSF)));
#pragma unroll
  for (int r = 0; r < 16; ++r) {
    char v = 0;
    if (r < 10) v = (WL[r * 1024 + j] >= 0.0f) ? (char)1 : (char)-1;
    WLb[r * 1024 + j] = v;
  }
}

// ---------------- main fused GEMM (fp4): out = binarize(BN(A @ Bt^T)) ----------------
// R5-verified structure on 512B fp4 rows: 128x128 tile, 4 waves 2x2 (each 2x2 of 32x32),
// 4 intervals x (4 MFMA-steps x 4 MFMA), LDS [128 rows][128B] linear dest + in-row XOR chunk
// swizzle (counter-verified conflict-free), two __syncthreads per interval. Epilogue multiplies
// acc by exact 1/lam, BN in numpy-f32 rounding, binarize. OUT_I8: i8 rows for gemm_fin.
template <int OUT_I8>
__global__ __launch_bounds__(256, 2)
void gemm_bin(const unsigned char* __restrict__ A, const unsigned char* __restrict__ Bt,
              unsigned char* __restrict__ Cb,
              const float* __restrict__ mean, const float* __restrict__ beta,
              const float* __restrict__ invstd, const float* __restrict__ lam_inv) {
  __shared__ char lds[32768];  // A [0,16384), B [16384,32768)
  const int tid = threadIdx.x;
  const int lane = tid & 63;
  const int wave = tid >> 6;
  const int d = blockIdx.x;  // 0..4095
  const int xcd = d & 7;
  const int idx = d >> 3;
  const int bm = xcd * 64 + (idx >> 3);
  const int bn = idx & 7;
  const int wm = wave >> 1, wn = wave & 1;
  const int h = lane >> 5, r31 = lane & 31;

  const int srow = tid >> 3;  // 0..31
  const int schunk = ((tid & 7) ^ (srow & 7)) << 4;
  const unsigned char* gA = A + (size_t)(bm * 128 + srow) * 512 + schunk;
  const unsigned char* gB = Bt + (size_t)(bn * 128 + srow) * 512 + schunk;
  const int lwoff = (tid & ~63) * 16;

  const float li = *lam_inv;

  f32x16 acc00 = (f32x16)0.0f, acc01 = (f32x16)0.0f;
  f32x16 acc10 = (f32x16)0.0f, acc11 = (f32x16)0.0f;

  const int arow = (wm * 64 + r31) * 128;
  const int brow = 16384 + (wn * 64 + r31) * 128;

#pragma unroll
  for (int t = 0; t < 4; ++t) {
    const int ko = t * 128;
#pragma unroll
    for (int i = 0; i < 4; ++i) {
      gld_lds16(gA + ko + i * 16384, lds + lwoff + i * 4096);
      gld_lds16(gB + ko + i * 16384, lds + 16384 + lwoff + i * 4096);
    }
    __syncthreads();
#pragma unroll
    for (int s = 0; s < 4; ++s) {
      const int slot = (((s << 1) + h) ^ (r31 & 7)) << 4;
      i32x8 a0 = dup8(*(const i32x4*)(lds + arow + slot));
      i32x8 a1 = dup8(*(const i32x4*)(lds + arow + 4096 + slot));
      i32x8 b0 = dup8(*(const i32x4*)(lds + brow + slot));
      i32x8 b1 = dup8(*(const i32x4*)(lds + brow + 4096 + slot));
      acc00 = MFMA_FP4(a0, b0, acc00);
      acc01 = MFMA_FP4(a0, b1, acc01);
      acc10 = MFMA_FP4(a1, b0, acc10);
      acc11 = MFMA_FP4(a1, b1, acc11);
    }
    __syncthreads();
  }

  const int rbase = bm * 128 + wm * 64 + 4 * h;
  const int c0 = bn * 128 + wn * 64 + r31;
  const float mu0 = mean[c0], is0 = invstd[c0], be0 = beta[c0];
  const float mu1 = mean[c0 + 32], is1 = invstd[c0 + 32], be1 = beta[c0 + 32];
  const int cb = bn * 64 + wn * 32 + r31;
#pragma unroll
  for (int mt = 0; mt < 2; ++mt) {
    const f32x16 a0 = (mt == 0) ? acc00 : acc10;
    const f32x16 a1 = (mt == 0) ? acc01 : acc11;
#pragma unroll
    for (int r = 0; r < 16; ++r) {
      const int row = rbase + mt * 32 + (r & 3) + 8 * (r >> 2);
      float y0 = __fadd_rn(__fmul_rn(__fsub_rn(__fmul_rn(a0[r], li), mu0), is0), be0);
      float y1 = __fadd_rn(__fmul_rn(__fsub_rn(__fmul_rn(a1[r], li), mu1), is1), be1);
      if (OUT_I8) {
        Cb[(size_t)row * 1024 + c0] = (y0 >= 0.0f) ? 1 : 0xFF;
        Cb[(size_t)row * 1024 + c0 + 32] = (y1 >= 0.0f) ? 1 : 0xFF;
      } else {
        unsigned nl = (y0 >= 0.0f) ? 2u : 10u;
        unsigned nh = (y1 >= 0.0f) ? 2u : 10u;
        Cb[(size_t)row * 512 + cb] = (unsigned char)(nl | (nh << 4));
      }
    }
  }
}

// ---------------- final layer: out[65536][10] = BN(A @ WLb^T), fp32 out, i8 inputs (R2-verified) ----
__global__ __launch_bounds__(256, 2)
void gemm_fin(const char* __restrict__ A, const char* __restrict__ BtL,
              float* __restrict__ out,
              const float* __restrict__ meanL, const float* __restrict__ betaL,
              const float* __restrict__ invstdL) {
  constexpr int K = 1024;
  __shared__ char sA[128 * 64];
  __shared__ char sB[16 * 64];
  const int tid = threadIdx.x;
  const int lane = tid & 63;
  const int wave = tid >> 6;
  const int bm = blockIdx.x;

  const int sr = tid >> 2;
  const int csrc = ((tid & 3) ^ (sr & 3)) << 4;
  const char* gA = A + (size_t)(bm * 128 + sr) * K + csrc;
  const char* gB = BtL + (size_t)sr * K + csrc;
  char* lA = sA + (tid & ~63) * 16;
  char* lB = sB;

  const int slot = ((lane >> 4) ^ (lane & 3)) << 4;
  const char* rA = sA + (wave * 32 + (lane & 15)) * 64 + slot;
  const char* rB = sB + (lane & 15) * 64 + slot;

  i32x4 acc0 = (i32x4)0, acc1 = (i32x4)0;

  for (int k0 = 0; k0 < K; k0 += 64) {
    gld_lds16(gA, lA);
    gld_lds16(gA + (size_t)64 * K, lA + 4096);
    if (tid < 64) gld_lds16(gB, lB);
    gA += 64;
    gB += 64;
    __syncthreads();
    i32x4 af0 = *(const i32x4*)(rA);
    i32x4 af1 = *(const i32x4*)(rA + 16 * 64);
    i32x4 b0 = *(const i32x4*)(rB);
    acc0 = __builtin_amdgcn_mfma_i32_16x16x64_i8(af0, b0, acc0, 0, 0, 0);
    acc1 = __builtin_amdgcn_mfma_i32_16x16x64_i8(af1, b0, acc1, 0, 0, 0);
    __syncthreads();
  }

  const int col = lane & 15;
  if (col < 10) {
    const float mu = meanL[col], is = invstdL[col], be = betaL[col];
    const int r0 = bm * 128 + wave * 32 + ((lane >> 4) << 2);
#pragma unroll
    for (int m = 0; m < 2; ++m) {
      const i32x4 a = (m == 0) ? acc0 : acc1;
#pragma unroll
      for (int j = 0; j < 4; ++j) {
        const int row = r0 + m * 16 + j;
        out[(size_t)row * 10 + col] = __fadd_rn(__fmul_rn(__fsub_rn((float)a[j], mu), is), be);
      }
    }
  }
}

extern "C" void kernel_launch(void* const* d_in, const int* in_sizes, int n_in,
                              void* d_out, int out_size, void* d_ws, size_t ws_size,
                              hipStream_t stream) {
  const float* x = (const float*)d_in[0];
  const float* W0 = (const float*)d_in[1];
  const float* Wh = (const float*)d_in[2];
  const float* WL = (const float*)d_in[3];
  const float* bn_gamma = (const float*)d_in[4];
  const float* bn_beta = (const float*)d_in[5];
  const float* bn_mean = (const float*)d_in[6];
  const float* bn_var = (const float*)d_in[7];
  const float* bnL_gamma = (const float*)d_in[8];
  const float* bnL_beta = (const float*)d_in[9];
  const float* bnL_mean = (const float*)d_in[10];
  const float* bnL_var = (const float*)d_in[11];
  float* out = (float*)d_out;

  // workspace (~130 MB)
  char* ws = (char*)d_ws;
  unsigned char* X0f4 = (unsigned char*)ws;                    // 32 MiB
  unsigned char* X1f4 = (unsigned char*)(ws + 33554432);       // 32 MiB
  unsigned char* Xi8 = (unsigned char*)(ws + 67108864);        // 64 MiB
  char* wbase = ws + 134217728;
  unsigned char* Wf4 = (unsigned char*)wbase;                  // 3 x 512 KiB
  char* WLb = wbase + 3 * 524288;                              // 16 KiB
  float* invstd3 = (float*)(wbase + 3 * 524288 + 16384);       // 12 KiB
  float* invstdL = invstd3 + 3 * 1024;
  float* lam_inv = invstdL + 16;
  unsigned char* T = (unsigned char*)(lam_inv + 16);           // 64 B

  hipLaunchKernelGGL(k_prep, dim3(1), dim3(1024), 0, stream,
                     bn_gamma, bn_var, bnL_gamma, bnL_var, WL, invstd3, invstdL, WLb);
  hipLaunchKernelGGL(k_probe, dim3(1), dim3(64), 0, stream, T, lam_inv);
  hipLaunchKernelGGL(k_packW, dim3(128, 3), dim3(256), 0, stream, W0, Wh, T, Wf4);
  hipLaunchKernelGGL(k_pack, dim3(8192), dim3(256), 0, stream, x, X0f4, 784, 0.5f);

  hipLaunchKernelGGL((gemm_bin<0>), dim3(4096), dim3(256), 0, stream, X0f4, Wf4, X1f4,
                     bn_mean, bn_beta, invstd3, lam_inv);
  hipLaunchKernelGGL((gemm_bin<0>), dim3(4096), dim3(256), 0, stream, X1f4, Wf4 + 524288, X0f4,
                     bn_mean + 1024, bn_beta + 1024, invstd3 + 1024, lam_inv);
  hipLaunchKernelGGL((gemm_bin<1>), dim3(4096), dim3(256), 0, stream, X0f4, Wf4 + 2 * 524288, Xi8,
                     bn_mean + 2048, bn_beta + 2048, invstd3 + 2048, lam_inv);
  hipLaunchKernelGGL(gemm_fin, dim3(512), dim3(256), 0, stream, (const char*)Xi8, (const char*)WLb,
                     out, bnL_mean, bnL_beta, invstdL);
}